// Round 5
// baseline (721.513 us; speedup 1.0000x reference)
//
#include <hip/hip_runtime.h>

// MPLayer v9: edge-contiguous z_csr waves + fused CSR-build kernels.
//   z_csr: wave w owns pair slots [w*128, w*128+128); binary-search cursor for
//   its node range; pairs stream sequentially (L1-hot across nodes) so the
//   per-node cold pair-load stall disappears; gathers stay 8-deep.
//   dg derived as cursor[n+1]-cursor[n] (cursor = start offsets).
//   Build: hist8 -> scan_part(+sum8) -> scan_top -> scan_local(+c8) -> permute.
// Fallback (ws too small): R1 atomic scatter + same epilogues.

#define N_NODES 100000
#define N_EDGES 1600000
#define ND 32
#define ED 32
#define OD 32
#define ZD 64
#define NTILE 98      // ceil(N_NODES/1024)
#define SLOTS 128     // pair slots per wave in z_csr
#define NWAVE (N_EDGES / SLOTS + 1)   // +1 wave for trailing deg-0 nodes

__device__ inline float bcast(float v, int lane) {
    return __uint_as_float(__builtin_amdgcn_readlane(__float_as_uint(v), lane));
}

// ---------- CSR build ----------
__global__ __launch_bounds__(256) void hist8(const int* __restrict__ dst,
                                             int* __restrict__ h8) {
    int e = blockIdx.x * 256 + threadIdx.x;
    if (e < N_EDGES)
        atomicAdd(&h8[(blockIdx.x & 7) * N_NODES + dst[e]], 1);
}

// sums the 8 histogram copies -> cnt, and reduces per-block totals -> part
__global__ __launch_bounds__(1024) void scan_part(const int* __restrict__ h8,
                                                  int* __restrict__ cnt,
                                                  int* __restrict__ part) {
    __shared__ int s[1024];
    int i = blockIdx.x * 1024 + threadIdx.x;
    int v = 0;
    if (i < N_NODES) {
        #pragma unroll
        for (int x = 0; x < 8; ++x) v += h8[x * N_NODES + i];
        cnt[i] = v;
    }
    s[threadIdx.x] = v;
    __syncthreads();
    for (int off = 512; off > 0; off >>= 1) {
        if (threadIdx.x < off) s[threadIdx.x] += s[threadIdx.x + off];
        __syncthreads();
    }
    if (threadIdx.x == 0) part[blockIdx.x] = s[0];
}

__global__ void scan_top(int* part) {   // 1 block, 128 threads, NTILE<=128
    __shared__ int s[128];
    int v = (threadIdx.x < NTILE) ? part[threadIdx.x] : 0;
    s[threadIdx.x] = v;
    __syncthreads();
    for (int off = 1; off < 128; off <<= 1) {
        int u = (threadIdx.x >= off) ? s[threadIdx.x - off] : 0;
        __syncthreads();
        s[threadIdx.x] += u;
        __syncthreads();
    }
    if (threadIdx.x < NTILE) part[threadIdx.x] = s[threadIdx.x] - v;  // exclusive
}

// exclusive scan -> cursor (start offsets), and per-copy cursors c8
__global__ __launch_bounds__(1024) void scan_local(const int* __restrict__ cnt,
                                                   const int* __restrict__ part,
                                                   const int* __restrict__ h8,
                                                   int* __restrict__ cursor,
                                                   int* __restrict__ c8) {
    __shared__ int s[1024];
    int i = blockIdx.x * 1024 + threadIdx.x;
    int v = (i < N_NODES) ? cnt[i] : 0;
    s[threadIdx.x] = v;
    __syncthreads();
    for (int off = 1; off < 1024; off <<= 1) {
        int u = (threadIdx.x >= off) ? s[threadIdx.x - off] : 0;
        __syncthreads();
        s[threadIdx.x] += u;
        __syncthreads();
    }
    if (i < N_NODES) {
        int run = part[blockIdx.x] + s[threadIdx.x] - v;   // start offset
        cursor[i] = run;
        #pragma unroll
        for (int x = 0; x < 8; ++x) {
            c8[x * N_NODES + i] = run;
            run += h8[x * N_NODES + i];
        }
    }
}

// ---------- permute: 1 thread per edge, IDs only, split cursors ----------
__global__ __launch_bounds__(256) void permute_ids(
    const int* __restrict__ src, const int* __restrict__ dst,
    int* __restrict__ c8, int2* __restrict__ pair)
{
    int e = blockIdx.x * 256 + threadIdx.x;
    if (e >= N_EDGES) return;
    int pos = atomicAdd(&c8[(blockIdx.x & 7) * N_NODES + dst[e]], 1);
    pair[pos] = make_int2(src[e], e);          // 8B scattered store, L2-sized buf
}

// ---------- fused aggregate + z: edge-contiguous wave ranges ----------
__device__ inline int lbound(const int* __restrict__ cur, int x) {
    // first n in [0, N_NODES] with start[n] >= x, where start[N_NODES] = N_EDGES
    int lo = 0, hi = N_NODES;
    while (lo < hi) {
        int mid = (lo + hi) >> 1;
        if (cur[mid] < x) lo = mid + 1; else hi = mid;
    }
    return lo;
}

__global__ __launch_bounds__(256, 1) void z_csr(
    const float* __restrict__ node_x, const float* __restrict__ edge_x,
    const float* __restrict__ z_init,
    const float* __restrict__ W_pre, const float* __restrict__ b_pre,
    const int* __restrict__ cursor,            // start offsets (immutable)
    const int2* __restrict__ pair, float* __restrict__ zbuf)
{
    const int l = threadIdx.x & 63;
    float Wp[ZD];
    #pragma unroll
    for (int k = 0; k < ZD; ++k) Wp[k] = W_pre[k * ZD + l];
    const float bp = b_pre[l];
    // lane-independent base per half (ND==ED==32):
    //   l <  32: gbase[sel*32 + l] = node_x[sel*32 + l]
    //   l >= 32: gbase[sel*32 + l] = edge_x[sel*32 + (l-32)]
    const float* __restrict__ gbase = (l < ND) ? node_x : (edge_x - ND);

    int w = ((blockIdx.x * 256 + threadIdx.x) >> 6);
    if (w >= NWAVE) return;
    int lo = w * SLOTS;
    int n0 = lbound(cursor, lo);
    int n1 = lbound(cursor, lo + SLOTS);

    for (int n = n0; n < n1; ++n) {
        int j   = cursor[n];
        int end = (n + 1 < N_NODES) ? cursor[n + 1] : N_EDGES;
        int dg  = end - j;
        float z;
        if (dg > 0) {
            float acc = 0.0f;
            for (; j + 8 <= end; j += 8) {          // 16 lines in flight
                int2 p0 = pair[j],   p1 = pair[j+1], p2 = pair[j+2], p3 = pair[j+3];
                int2 p4 = pair[j+4], p5 = pair[j+5], p6 = pair[j+6], p7 = pair[j+7];
                int s0 = (l < ND) ? p0.x : p0.y;
                int s1 = (l < ND) ? p1.x : p1.y;
                int s2 = (l < ND) ? p2.x : p2.y;
                int s3 = (l < ND) ? p3.x : p3.y;
                int s4 = (l < ND) ? p4.x : p4.y;
                int s5 = (l < ND) ? p5.x : p5.y;
                int s6 = (l < ND) ? p6.x : p6.y;
                int s7 = (l < ND) ? p7.x : p7.y;
                float v0 = gbase[(unsigned)s0 * 32u + (unsigned)l];
                float v1 = gbase[(unsigned)s1 * 32u + (unsigned)l];
                float v2 = gbase[(unsigned)s2 * 32u + (unsigned)l];
                float v3 = gbase[(unsigned)s3 * 32u + (unsigned)l];
                float v4 = gbase[(unsigned)s4 * 32u + (unsigned)l];
                float v5 = gbase[(unsigned)s5 * 32u + (unsigned)l];
                float v6 = gbase[(unsigned)s6 * 32u + (unsigned)l];
                float v7 = gbase[(unsigned)s7 * 32u + (unsigned)l];
                acc += ((v0 + v1) + (v2 + v3)) + ((v4 + v5) + (v6 + v7));
            }
            for (; j < end; ++j) {
                int2 p0 = pair[j];
                int s0 = (l < ND) ? p0.x : p0.y;
                acc += gbase[(unsigned)s0 * 32u + (unsigned)l];
            }
            float a0 = (float)dg * bp, a1 = 0.0f;
            #pragma unroll
            for (int k = 0; k < ZD; k += 2) {
                a0 += bcast(acc, k)     * Wp[k];
                a1 += bcast(acc, k + 1) * Wp[k + 1];
            }
            z = fmaxf(a0 + a1, 0.0f);
        } else {
            z = z_init[(long)n * ZD + l];
        }
        zbuf[(long)n * ZD + l] = z;
    }
}

// ---------- fallback: R1 atomic scatter + dense z ----------
__global__ __launch_bounds__(256) void edge_scatter(
    const float* __restrict__ node_x, const float* __restrict__ edge_x,
    const int* __restrict__ src, const int* __restrict__ dst,
    float* __restrict__ S, int* __restrict__ degI)
{
    long t = (long)blockIdx.x * 256 + threadIdx.x;
    int e = (int)(t >> 6), l = (int)(t & 63);
    if (e >= N_EDGES) return;
    int s = src[e], d = dst[e];
    float v = (l < ND) ? node_x[(long)s * ND + l] : edge_x[(long)e * ED + (l - ND)];
    atomicAdd(&S[(long)d * ZD + l], v);
    if (l == 0) atomicAdd(&degI[d], 1);
}

__global__ __launch_bounds__(256, 1) void z_dense(
    const float* __restrict__ z_init,
    const float* __restrict__ W_pre, const float* __restrict__ b_pre,
    float* __restrict__ S, const int* __restrict__ degI)
{
    const int l = threadIdx.x & 63;
    float Wp[ZD];
    #pragma unroll
    for (int k = 0; k < ZD; ++k) Wp[k] = W_pre[k * ZD + l];
    const float bp = b_pre[l];
    int w  = (blockIdx.x * 256 + threadIdx.x) >> 6;
    int nw = (gridDim.x * 256) >> 6;
    for (int n = w; n < N_NODES; n += nw) {
        int dg = degI[n];
        float sv = S[(long)n * ZD + l];
        float z;
        if (dg > 0) {
            float a0 = (float)dg * bp, a1 = 0.0f;
            #pragma unroll
            for (int k = 0; k < ZD; k += 2) {
                a0 += bcast(sv, k)     * Wp[k];
                a1 += bcast(sv, k + 1) * Wp[k + 1];
            }
            z = fmaxf(a0 + a1, 0.0f);
        } else {
            z = z_init[(long)n * ZD + l];
        }
        S[(long)n * ZD + l] = z;   // in-place: wave owns row
    }
}

// ---------- shared h update ----------
__global__ __launch_bounds__(256, 1) void h_upd(
    const float* __restrict__ node_x,
    const float* __restrict__ W_upd, const float* __restrict__ b_upd,
    const float* __restrict__ zbuf, float* __restrict__ out)
{
    const int l = threadIdx.x & 63;
    const int c = l & 31;
    float Wu[ND + ZD];   // 96
    #pragma unroll
    for (int k = 0; k < ND + ZD; ++k) Wu[k] = W_upd[k * OD + c];
    const float bu = b_upd[c];
    int w  = (blockIdx.x * 256 + threadIdx.x) >> 6;
    int nw = (gridDim.x * 256) >> 6;
    for (int n = w; n < N_NODES; n += nw) {
        float zv = zbuf[(long)n * ZD + l];
        float xv = node_x[(long)n * ND + c];
        float h0 = bu, h1 = 0.0f;
        #pragma unroll
        for (int k = 0; k < ND; k += 2) {
            h0 += bcast(xv, k)     * Wu[k];
            h1 += bcast(xv, k + 1) * Wu[k + 1];
        }
        #pragma unroll
        for (int k = 0; k < ZD; k += 2) {
            h0 += bcast(zv, k)     * Wu[ND + k];
            h1 += bcast(zv, k + 1) * Wu[ND + k + 1];
        }
        if (l < OD) out[(long)n * OD + l] = fmaxf(h0 + h1, 0.0f);
    }
}

extern "C" void kernel_launch(void* const* d_in, const int* in_sizes, int n_in,
                              void* d_out, int out_size, void* d_ws, size_t ws_size,
                              hipStream_t stream)
{
    const float* node_x = (const float*)d_in[0];
    const float* edge_x = (const float*)d_in[1];
    const float* z_init = (const float*)d_in[2];
    const float* W_pre  = (const float*)d_in[3];
    const float* b_pre  = (const float*)d_in[4];
    const float* W_upd  = (const float*)d_in[5];
    const float* b_upd  = (const float*)d_in[6];
    const int*   src    = (const int*)d_in[7];
    const int*   dst    = (const int*)d_in[8];
    float* out = (float*)d_out;

    // CSR-path ws layout: pair[E]int2 | zbuf[N*64]f | cnt[N]i | part[128]i |
    //                     cursor[N]i | h8[8N]i | c8[8N]i   (~46 MB)
    size_t need = (size_t)N_EDGES * sizeof(int2)
                + (size_t)N_NODES * ZD * sizeof(float)
                + ((size_t)18 * N_NODES + 128) * sizeof(int);

    if (ws_size >= need) {
        int2*  pair   = (int2*)d_ws;
        float* zbuf   = (float*)(pair + N_EDGES);
        int*   cnt    = (int*)(zbuf + (size_t)N_NODES * ZD);
        int*   part   = cnt + N_NODES;
        int*   cursor = part + 128;
        int*   h8     = cursor + N_NODES;
        int*   c8     = h8 + 8 * N_NODES;

        (void)hipMemsetAsync(h8, 0, 8 * N_NODES * sizeof(int), stream);
        hist8<<<(N_EDGES + 255) / 256, 256, 0, stream>>>(dst, h8);
        scan_part<<<NTILE, 1024, 0, stream>>>(h8, cnt, part);
        scan_top<<<1, 128, 0, stream>>>(part);
        scan_local<<<NTILE, 1024, 0, stream>>>(cnt, part, h8, cursor, c8);
        permute_ids<<<(N_EDGES + 255) / 256, 256, 0, stream>>>(src, dst, c8, pair);
        z_csr<<<(NWAVE * 64 + 255) / 256, 256, 0, stream>>>(
            node_x, edge_x, z_init, W_pre, b_pre, cursor, pair, zbuf);
        h_upd<<<2048, 256, 0, stream>>>(node_x, W_upd, b_upd, zbuf, out);
    } else {
        // Fallback (~26 MB): S[N*64]f | degI[N]i
        float* S    = (float*)d_ws;
        int*   degI = (int*)(S + (size_t)N_NODES * ZD);
        (void)hipMemsetAsync(d_ws, 0,
            ((size_t)N_NODES * ZD + N_NODES) * sizeof(float), stream);
        edge_scatter<<<(int)(((long)N_EDGES * 64 + 255) / 256), 256, 0, stream>>>(
            node_x, edge_x, src, dst, S, degI);
        z_dense<<<2048, 256, 0, stream>>>(z_init, W_pre, b_pre, S, degI);
        h_upd<<<2048, 256, 0, stream>>>(node_x, W_upd, b_upd, S, out);
    }
}

// Round 6
// 589.545 us; speedup vs baseline: 1.2238x; 1.2238x over previous
//
#include <hip/hip_runtime.h>

// MPLayer v10: float4-lane z_csr gather (4 edges per wave-load).
//   v8 z_csr issued 1 HBM line per gather instr (32 lanes = one 128B row);
//   MLP-limited at ~1.1TB/s. Now: lane l -> colgroup c=l&7, half h=(l>>3)&1,
//   slot s=l>>4; one float4 gather = 4 edge lines + 4 node lines in flight.
//   16-edge iterations, clamp+mask tail, 8x shfl_xor slot-reduce, matvec via
//   static readlane (element k = lane (k>>5)*8+((k&31)>>2), comp k&3).
//   Build pipeline = v9's fused 8-dispatch chain (neutral, fewer launches).
// Fallback (ws too small): R1 atomic scatter + same epilogues.

#define N_NODES 100000
#define N_EDGES 1600000
#define ND 32
#define ED 32
#define OD 32
#define ZD 64
#define NTILE 98      // ceil(N_NODES/1024)

__device__ inline float bcast(float v, int lane) {
    return __uint_as_float(__builtin_amdgcn_readlane(__float_as_uint(v), lane));
}

// ---------- CSR build ----------
__global__ __launch_bounds__(256) void hist8(const int* __restrict__ dst,
                                             int* __restrict__ h8) {
    int e = blockIdx.x * 256 + threadIdx.x;
    if (e < N_EDGES)
        atomicAdd(&h8[(blockIdx.x & 7) * N_NODES + dst[e]], 1);
}

// sums the 8 histogram copies -> cnt, and reduces per-block totals -> part
__global__ __launch_bounds__(1024) void scan_part(const int* __restrict__ h8,
                                                  int* __restrict__ cnt,
                                                  int* __restrict__ part) {
    __shared__ int s[1024];
    int i = blockIdx.x * 1024 + threadIdx.x;
    int v = 0;
    if (i < N_NODES) {
        #pragma unroll
        for (int x = 0; x < 8; ++x) v += h8[x * N_NODES + i];
        cnt[i] = v;
    }
    s[threadIdx.x] = v;
    __syncthreads();
    for (int off = 512; off > 0; off >>= 1) {
        if (threadIdx.x < off) s[threadIdx.x] += s[threadIdx.x + off];
        __syncthreads();
    }
    if (threadIdx.x == 0) part[blockIdx.x] = s[0];
}

__global__ void scan_top(int* part) {   // 1 block, 128 threads, NTILE<=128
    __shared__ int s[128];
    int v = (threadIdx.x < NTILE) ? part[threadIdx.x] : 0;
    s[threadIdx.x] = v;
    __syncthreads();
    for (int off = 1; off < 128; off <<= 1) {
        int u = (threadIdx.x >= off) ? s[threadIdx.x - off] : 0;
        __syncthreads();
        s[threadIdx.x] += u;
        __syncthreads();
    }
    if (threadIdx.x < NTILE) part[threadIdx.x] = s[threadIdx.x] - v;  // exclusive
}

// exclusive scan -> cursor (start offsets), and per-copy cursors c8
__global__ __launch_bounds__(1024) void scan_local(const int* __restrict__ cnt,
                                                   const int* __restrict__ part,
                                                   const int* __restrict__ h8,
                                                   int* __restrict__ cursor,
                                                   int* __restrict__ c8) {
    __shared__ int s[1024];
    int i = blockIdx.x * 1024 + threadIdx.x;
    int v = (i < N_NODES) ? cnt[i] : 0;
    s[threadIdx.x] = v;
    __syncthreads();
    for (int off = 1; off < 1024; off <<= 1) {
        int u = (threadIdx.x >= off) ? s[threadIdx.x - off] : 0;
        __syncthreads();
        s[threadIdx.x] += u;
        __syncthreads();
    }
    if (i < N_NODES) {
        int run = part[blockIdx.x] + s[threadIdx.x] - v;   // start offset
        cursor[i] = run;
        #pragma unroll
        for (int x = 0; x < 8; ++x) {
            c8[x * N_NODES + i] = run;
            run += h8[x * N_NODES + i];
        }
    }
}

// ---------- permute: 1 thread per edge, IDs only, split cursors ----------
__global__ __launch_bounds__(256) void permute_ids(
    const int* __restrict__ src, const int* __restrict__ dst,
    int* __restrict__ c8, int2* __restrict__ pair)
{
    int e = blockIdx.x * 256 + threadIdx.x;
    if (e >= N_EDGES) return;
    int pos = atomicAdd(&c8[(blockIdx.x & 7) * N_NODES + dst[e]], 1);
    pair[pos] = make_int2(src[e], e);          // 8B scattered store, L2-sized buf
}

// ---------- fused aggregate + z: float4-lane gather ----------
__global__ __launch_bounds__(256, 1) void z_csr(
    const float* __restrict__ node_x, const float* __restrict__ edge_x,
    const float* __restrict__ z_init,
    const float* __restrict__ W_pre, const float* __restrict__ b_pre,
    const int* __restrict__ cnt, const int* __restrict__ cursor,  // cursor = START
    const int2* __restrict__ pair, float* __restrict__ zbuf)
{
    const int l = threadIdx.x & 63;
    const int c = l & 7;            // column group: float4 covering cols 4c..4c+3
    const int h = (l >> 3) & 1;     // 0 = node half, 1 = edge half
    const int s = l >> 4;           // edge slot 0..3
    const float4* __restrict__ b4 =
        h ? (const float4*)edge_x : (const float4*)node_x;

    float Wp[ZD];
    #pragma unroll
    for (int k = 0; k < ZD; ++k) Wp[k] = W_pre[k * ZD + l];
    const float bp = b_pre[l];

    int w  = (blockIdx.x * 256 + threadIdx.x) >> 6;
    int nw = (gridDim.x * 256) >> 6;
    for (int n = w; n < N_NODES; n += nw) {
        int dg = cnt[n];
        float z;
        if (dg > 0) {
            int j0  = cursor[n];
            int end = j0 + dg;
            float4 acc = make_float4(0.f, 0.f, 0.f, 0.f);
            for (int j = j0; j < end; j += 16) {
                // this lane's 4 edge indices (slots s, s+4, s+8, s+12 of chunk)
                #pragma unroll
                for (int u = 0; u < 4; ++u) {
                    int ei   = j + 4 * u + s;
                    int cl   = (ei < end) ? ei : (end - 1);
                    int2 q   = pair[cl];                  // 4 distinct 8B addrs
                    int row  = h ? q.y : q.x;
                    float4 v = b4[(unsigned)row * 8u + (unsigned)c];
                    float  m = (ei < end) ? 1.0f : 0.0f;
                    acc.x += v.x * m;
                    acc.y += v.y * m;
                    acc.z += v.z * m;
                    acc.w += v.w * m;
                }
            }
            // reduce across the 4 slots (lanes l, l^16, l^32, l^48)
            acc.x += __shfl_xor(acc.x, 16); acc.y += __shfl_xor(acc.y, 16);
            acc.z += __shfl_xor(acc.z, 16); acc.w += __shfl_xor(acc.w, 16);
            acc.x += __shfl_xor(acc.x, 32); acc.y += __shfl_xor(acc.y, 32);
            acc.z += __shfl_xor(acc.z, 32); acc.w += __shfl_xor(acc.w, 32);
            // matvec: element k lives in lane (k>>5)*8 + ((k&31)>>2), comp k&3
            float a0 = (float)dg * bp, a1 = 0.0f;
            #pragma unroll
            for (int k = 0; k < ZD; k += 2) {
                const int sl0 = (k >> 5) * 8 + ((k & 31) >> 2);
                const float cv0 = ((k & 3) == 0) ? acc.x :
                                  ((k & 3) == 1) ? acc.y :
                                  ((k & 3) == 2) ? acc.z : acc.w;
                const int k1 = k + 1;
                const int sl1 = (k1 >> 5) * 8 + ((k1 & 31) >> 2);
                const float cv1 = ((k1 & 3) == 0) ? acc.x :
                                  ((k1 & 3) == 1) ? acc.y :
                                  ((k1 & 3) == 2) ? acc.z : acc.w;
                a0 += bcast(cv0, sl0) * Wp[k];
                a1 += bcast(cv1, sl1) * Wp[k1];
            }
            z = fmaxf(a0 + a1, 0.0f);
        } else {
            z = z_init[(long)n * ZD + l];
        }
        zbuf[(long)n * ZD + l] = z;
    }
}

// ---------- fallback: R1 atomic scatter + dense z ----------
__global__ __launch_bounds__(256) void edge_scatter(
    const float* __restrict__ node_x, const float* __restrict__ edge_x,
    const int* __restrict__ src, const int* __restrict__ dst,
    float* __restrict__ S, int* __restrict__ degI)
{
    long t = (long)blockIdx.x * 256 + threadIdx.x;
    int e = (int)(t >> 6), l = (int)(t & 63);
    if (e >= N_EDGES) return;
    int s = src[e], d = dst[e];
    float v = (l < ND) ? node_x[(long)s * ND + l] : edge_x[(long)e * ED + (l - ND)];
    atomicAdd(&S[(long)d * ZD + l], v);
    if (l == 0) atomicAdd(&degI[d], 1);
}

__global__ __launch_bounds__(256, 1) void z_dense(
    const float* __restrict__ z_init,
    const float* __restrict__ W_pre, const float* __restrict__ b_pre,
    float* __restrict__ S, const int* __restrict__ degI)
{
    const int l = threadIdx.x & 63;
    float Wp[ZD];
    #pragma unroll
    for (int k = 0; k < ZD; ++k) Wp[k] = W_pre[k * ZD + l];
    const float bp = b_pre[l];
    int w  = (blockIdx.x * 256 + threadIdx.x) >> 6;
    int nw = (gridDim.x * 256) >> 6;
    for (int n = w; n < N_NODES; n += nw) {
        int dg = degI[n];
        float sv = S[(long)n * ZD + l];
        float z;
        if (dg > 0) {
            float a0 = (float)dg * bp, a1 = 0.0f;
            #pragma unroll
            for (int k = 0; k < ZD; k += 2) {
                a0 += bcast(sv, k)     * Wp[k];
                a1 += bcast(sv, k + 1) * Wp[k + 1];
            }
            z = fmaxf(a0 + a1, 0.0f);
        } else {
            z = z_init[(long)n * ZD + l];
        }
        S[(long)n * ZD + l] = z;   // in-place: wave owns row
    }
}

// ---------- shared h update ----------
__global__ __launch_bounds__(256, 1) void h_upd(
    const float* __restrict__ node_x,
    const float* __restrict__ W_upd, const float* __restrict__ b_upd,
    const float* __restrict__ zbuf, float* __restrict__ out)
{
    const int l = threadIdx.x & 63;
    const int c = l & 31;
    float Wu[ND + ZD];   // 96
    #pragma unroll
    for (int k = 0; k < ND + ZD; ++k) Wu[k] = W_upd[k * OD + c];
    const float bu = b_upd[c];
    int w  = (blockIdx.x * 256 + threadIdx.x) >> 6;
    int nw = (gridDim.x * 256) >> 6;
    for (int n = w; n < N_NODES; n += nw) {
        float zv = zbuf[(long)n * ZD + l];
        float xv = node_x[(long)n * ND + c];
        float h0 = bu, h1 = 0.0f;
        #pragma unroll
        for (int k = 0; k < ND; k += 2) {
            h0 += bcast(xv, k)     * Wu[k];
            h1 += bcast(xv, k + 1) * Wu[k + 1];
        }
        #pragma unroll
        for (int k = 0; k < ZD; k += 2) {
            h0 += bcast(zv, k)     * Wu[ND + k];
            h1 += bcast(zv, k + 1) * Wu[ND + k + 1];
        }
        if (l < OD) out[(long)n * OD + l] = fmaxf(h0 + h1, 0.0f);
    }
}

extern "C" void kernel_launch(void* const* d_in, const int* in_sizes, int n_in,
                              void* d_out, int out_size, void* d_ws, size_t ws_size,
                              hipStream_t stream)
{
    const float* node_x = (const float*)d_in[0];
    const float* edge_x = (const float*)d_in[1];
    const float* z_init = (const float*)d_in[2];
    const float* W_pre  = (const float*)d_in[3];
    const float* b_pre  = (const float*)d_in[4];
    const float* W_upd  = (const float*)d_in[5];
    const float* b_upd  = (const float*)d_in[6];
    const int*   src    = (const int*)d_in[7];
    const int*   dst    = (const int*)d_in[8];
    float* out = (float*)d_out;

    // CSR-path ws layout: pair[E]int2 | zbuf[N*64]f | cnt[N]i | part[128]i |
    //                     cursor[N]i | h8[8N]i | c8[8N]i   (~46 MB)
    size_t need = (size_t)N_EDGES * sizeof(int2)
                + (size_t)N_NODES * ZD * sizeof(float)
                + ((size_t)18 * N_NODES + 128) * sizeof(int);

    if (ws_size >= need) {
        int2*  pair   = (int2*)d_ws;
        float* zbuf   = (float*)(pair + N_EDGES);
        int*   cnt    = (int*)(zbuf + (size_t)N_NODES * ZD);
        int*   part   = cnt + N_NODES;
        int*   cursor = part + 128;
        int*   h8     = cursor + N_NODES;
        int*   c8     = h8 + 8 * N_NODES;

        (void)hipMemsetAsync(h8, 0, 8 * N_NODES * sizeof(int), stream);
        hist8<<<(N_EDGES + 255) / 256, 256, 0, stream>>>(dst, h8);
        scan_part<<<NTILE, 1024, 0, stream>>>(h8, cnt, part);
        scan_top<<<1, 128, 0, stream>>>(part);
        scan_local<<<NTILE, 1024, 0, stream>>>(cnt, part, h8, cursor, c8);
        permute_ids<<<(N_EDGES + 255) / 256, 256, 0, stream>>>(src, dst, c8, pair);
        z_csr<<<2048, 256, 0, stream>>>(node_x, edge_x, z_init, W_pre, b_pre,
                                        cnt, cursor, pair, zbuf);
        h_upd<<<2048, 256, 0, stream>>>(node_x, W_upd, b_upd, zbuf, out);
    } else {
        // Fallback (~26 MB): S[N*64]f | degI[N]i
        float* S    = (float*)d_ws;
        int*   degI = (int*)(S + (size_t)N_NODES * ZD);
        (void)hipMemsetAsync(d_ws, 0,
            ((size_t)N_NODES * ZD + N_NODES) * sizeof(float), stream);
        edge_scatter<<<(int)(((long)N_EDGES * 64 + 255) / 256), 256, 0, stream>>>(
            node_x, edge_x, src, dst, S, degI);
        z_dense<<<2048, 256, 0, stream>>>(z_init, W_pre, b_pre, S, degI);
        h_upd<<<2048, 256, 0, stream>>>(node_x, W_upd, b_upd, S, out);
    }
}